// Round 20
// baseline (538.623 us; speedup 1.0000x reference)
//
#include <hip/hip_runtime.h>
#include <cstdint>
#include <cstddef>

typedef unsigned short u16;
typedef unsigned char u8;
typedef __bf16 bf16x8 __attribute__((ext_vector_type(8)));
typedef float f32x4 __attribute__((ext_vector_type(4)));
typedef float f32x2 __attribute__((ext_vector_type(2)));

constexpr int kN  = 4096;
constexpr int kE  = 131072;
constexpr int kET = kE + kN;   // with self loops
constexpr int kIn = 512;
constexpr int kC  = 256;
constexpr int kL  = 3;

constexpr int NSPLIT = 8;
constexpr int KSPAN  = kN / NSPLIT;  // 512 keys per split
constexpr int NSTEP  = KSPAN / 64;   // 8 steps of 64 keys

__device__ __forceinline__ u16 f2bf(float f) {
    unsigned u = __builtin_bit_cast(unsigned, f);
    u += 0x7fffu + ((u >> 16) & 1u);
    return (u16)(u >> 16);
}
__device__ __forceinline__ float bf2f(u16 s) {
    unsigned u = ((unsigned)s) << 16;
    return __builtin_bit_cast(float, u);
}
__device__ __forceinline__ float gelu_erf(float x) {
    return 0.5f * x * (1.f + erff(x * 0.70710678118654752f));
}
// async global->LDS, 16B per lane; ldst must be wave-uniform base (HW adds lane*16)
__device__ __forceinline__ void gload_lds16(const u16* gsrc, u16* ldst) {
    __builtin_amdgcn_global_load_lds(
        (const __attribute__((address_space(1))) unsigned int*)gsrc,
        (__attribute__((address_space(3))) unsigned int*)ldst, 16, 0, 0);
}
// sum over each row of 16 lanes via DPP row_ror adds (full-rate VALU, no LDS pipe)
__device__ __forceinline__ float dpp_ror_add16(float x) {
    int t;
    t = __builtin_amdgcn_update_dpp(0, __builtin_bit_cast(int, x), 0x121, 0xf, 0xf, true);
    x += __builtin_bit_cast(float, t);
    t = __builtin_amdgcn_update_dpp(0, __builtin_bit_cast(int, x), 0x122, 0xf, 0xf, true);
    x += __builtin_bit_cast(float, t);
    t = __builtin_amdgcn_update_dpp(0, __builtin_bit_cast(int, x), 0x124, 0xf, 0xf, true);
    x += __builtin_bit_cast(float, t);
    t = __builtin_amdgcn_update_dpp(0, __builtin_bit_cast(int, x), 0x128, 0xf, 0xf, true);
    x += __builtin_bit_cast(float, t);
    return x;
}
// sum over each 8-lane group: quad_perm xor1 + quad_perm xor2 + row_half_mirror (xor 7)
__device__ __forceinline__ float dpp_sum8(float x) {
    int t;
    t = __builtin_amdgcn_update_dpp(0, __builtin_bit_cast(int, x), 0xB1, 0xf, 0xf, true);
    x += __builtin_bit_cast(float, t);
    t = __builtin_amdgcn_update_dpp(0, __builtin_bit_cast(int, x), 0x4E, 0xf, 0xf, true);
    x += __builtin_bit_cast(float, t);
    t = __builtin_amdgcn_update_dpp(0, __builtin_bit_cast(int, x), 0x141, 0xf, 0xf, true);
    x += __builtin_bit_cast(float, t);
    return x;
}
// unpack 8 bf16 (uint4) -> 8 f32
__device__ __forceinline__ void unpack8(uint4 u, float* x) {
    x[0] = __builtin_bit_cast(float, u.x << 16);
    x[1] = __builtin_bit_cast(float, u.x & 0xffff0000u);
    x[2] = __builtin_bit_cast(float, u.y << 16);
    x[3] = __builtin_bit_cast(float, u.y & 0xffff0000u);
    x[4] = __builtin_bit_cast(float, u.z << 16);
    x[5] = __builtin_bit_cast(float, u.z & 0xffff0000u);
    x[6] = __builtin_bit_cast(float, u.w << 16);
    x[7] = __builtin_bit_cast(float, u.w & 0xffff0000u);
}
// unpack 4 fp8(e4m3) packed in a u32 -> 4 f32
__device__ __forceinline__ void unpack_fp8x4(unsigned wv, float* x) {
    f32x2 lo = __builtin_amdgcn_cvt_pk_f32_fp8(wv, false);
    f32x2 hi = __builtin_amdgcn_cvt_pk_f32_fp8(wv, true);
    x[0] = lo[0]; x[1] = lo[1]; x[2] = hi[0]; x[3] = hi[1];
}

// ---------------- fused fp32->bf16 cast of ALL weights + x + csr_count ------------
__global__ void cast_all(
    const float* __restrict__ x, const float* __restrict__ in_w,
    const float* __restrict__ gwl, const float* __restrict__ gwr,
    const float* __restrict__ minw, const float* __restrict__ moutw,
    const float* __restrict__ f1, const float* __restrict__ f2,
    const float* __restrict__ o1,
    u16* __restrict__ xbf, u16* __restrict__ wbf,
    const int* __restrict__ ei, int* __restrict__ cnt) {
    int i = blockIdx.x * 256 + threadIdx.x;
    if (i >= 1495040) return;
    if (i >= 1359872) {                     // csr_count region (kET edges)
        int e = i - 1359872;
        int d = (e < kE) ? ei[kE + e] : (e - kE);
        atomicAdd(cnt + d, 1);
        return;
    }
    const float* s;
    u16* dbase;
    int sj, dj;
    if (i < 524288) {                       // x: 4096x512
        s = x; dbase = xbf; sj = i; dj = i;
    } else if (i < 557056) {                // in_w
        s = in_w; dbase = wbf; sj = i - 524288; dj = sj;
    } else if (i < 753664) {                // gat_wl (interleaved)
        int j = i - 557056; int l = j >> 16, wi = j & 65535;
        s = gwl; dbase = wbf; sj = j; dj = 32768 + l * 131072 + wi;
    } else if (i < 950272) {                // gat_wr (interleaved, +65536)
        int j = i - 753664; int l = j >> 16, wi = j & 65535;
        s = gwr; dbase = wbf; sj = j; dj = 32768 + l * 131072 + 65536 + wi;
    } else if (i < 1097728) {               // mha_in_w
        s = minw; dbase = wbf; sj = i - 950272; dj = 425984 + sj;
    } else if (i < 1146880) {               // mha_out_w
        s = moutw; dbase = wbf; sj = i - 1097728; dj = 573440 + sj;
    } else if (i < 1245184) {               // ffn_w1
        s = f1; dbase = wbf; sj = i - 1146880; dj = 622592 + sj;
    } else if (i < 1343488) {               // ffn_w2
        s = f2; dbase = wbf; sj = i - 1245184; dj = 720896 + sj;
    } else {                                // out_w1
        s = o1; dbase = wbf; sj = i - 1343488; dj = 819200 + sj;
    }
    float4 v = ((const float4*)s)[sj];
    ushort4 o;
    o.x = f2bf(v.x); o.y = f2bf(v.y); o.z = f2bf(v.z); o.w = f2bf(v.w);
    ((ushort4*)dbase)[dj] = o;
}

// ---------------- CSR scan + scatter ----------------
__global__ __launch_bounds__(1024) void csr_scan(int* __restrict__ cnt_cur, int* __restrict__ off) {
    __shared__ int lds[1024];
    int t = threadIdx.x;
    int c[4], s = 0;
#pragma unroll
    for (int j = 0; j < 4; ++j) { c[j] = cnt_cur[t * 4 + j]; s += c[j]; }
    lds[t] = s;
    __syncthreads();
    for (int d = 1; d < 1024; d <<= 1) {
        int v = (t >= d) ? lds[t - d] : 0;
        __syncthreads();
        lds[t] += v;
        __syncthreads();
    }
    int excl = lds[t] - s;
#pragma unroll
    for (int j = 0; j < 4; ++j) { off[t * 4 + j] = excl; cnt_cur[t * 4 + j] = excl; excl += c[j]; }
    if (t == 1023) off[4096] = excl;
}

__global__ void csr_scatter(const int* __restrict__ ei, int* __restrict__ cur, int* __restrict__ csrc) {
    int e = blockIdx.x * 256 + threadIdx.x;
    if (e >= kET) return;
    int s, d;
    if (e < kE) { s = ei[e]; d = ei[kE + e]; } else { s = d = e - kE; }
    int pos = atomicAdd(cur + d, 1);
    csrc[pos] = s;
}

// ---------------- staged bf16 MFMA GEMM: C[M,N] = act(A[M,K] @ W[N,K]^T + bias) ----
template <int BM, int K, int ACT, int WF32, int WBF16>
__global__ __launch_bounds__(256) void gemm_st(
    const u16* __restrict__ A, const u16* __restrict__ W,
    const float* __restrict__ bias, float* __restrict__ Cf,
    u16* __restrict__ Cb, int N) {
    constexpr int BK = 32;
    constexpr int NK = K / BK;
    constexpr int MF = BM / 32;          // A fragments per wave
    int tid = threadIdx.x;
    int w = tid >> 6, lane = tid & 63;
    int wr = w >> 1, wc = w & 1;
    int g = lane >> 4, r = lane & 15;
    int bm = blockIdx.y * BM;
    int bn = blockIdx.x * 64;
    __shared__ __align__(16) u16 Ab[2][BM * BK];
    __shared__ __align__(16) u16 Bb[2][64 * BK];
    int srow = w * 16 + (lane >> 2);
    int scol = (lane & 3) * 8;
    auto stage = [&](int buf, int k0) {
#pragma unroll
        for (int i = 0; i < BM / 64; ++i)
            gload_lds16(A + (size_t)(bm + i * 64 + srow) * K + k0 + scol,
                        &Ab[buf][(i * 64 + w * 16) * BK]);
        gload_lds16(W + (size_t)(bn + srow) * K + k0 + scol, &Bb[buf][w * 16 * BK]);
    };
    f32x4 acc[MF][2] = {};
    stage(0, 0);
    __syncthreads();
    for (int st = 0; st < NK; ++st) {
        int cur = st & 1;
        if (st + 1 < NK) stage(cur ^ 1, (st + 1) * BK);
        const u16* Al = &Ab[cur][0];
        const u16* Bl = &Bb[cur][0];
        bf16x8 bf[2];
#pragma unroll
        for (int u = 0; u < 2; ++u)
            bf[u] = *(const bf16x8*)(Bl + (wc * 32 + u * 16 + r) * BK + g * 8);
#pragma unroll
        for (int t = 0; t < MF; ++t) {
            bf16x8 af = *(const bf16x8*)(Al + (wr * (BM / 2) + t * 16 + r) * BK + g * 8);
#pragma unroll
            for (int u = 0; u < 2; ++u)
                acc[t][u] = __builtin_amdgcn_mfma_f32_16x16x32_bf16(af, bf[u], acc[t][u], 0, 0, 0);
        }
        __syncthreads();
    }
    int r0 = bm + wr * (BM / 2) + g * 4;
    int c0 = bn + wc * 32 + r;
#pragma unroll
    for (int t = 0; t < MF; ++t)
#pragma unroll
        for (int u = 0; u < 2; ++u)
#pragma unroll
            for (int e = 0; e < 4; ++e) {
                int row = r0 + t * 16 + e, col = c0 + u * 16;
                float v = acc[t][u][e];
                if (bias) v += bias[col];
                if (ACT == 1) v = gelu_erf(v);
                if (WF32) Cf[(size_t)row * N + col] = v;
                if (WBF16) Cb[(size_t)row * N + col] = f2bf(v);
            }
}

// ---------------- fused qkv GEMM: writes Qb/Kb [head][n][64] and VTb [head][d][n] ---
__global__ __launch_bounds__(256) void gemm_qkv(
    const u16* __restrict__ A, const u16* __restrict__ W,
    const float* __restrict__ bias,
    u16* __restrict__ Qb, u16* __restrict__ Kb, u16* __restrict__ VTb) {
    constexpr int BK = 32, K = 256, NK = 8, BM = 128, MF = 4;
    int tid = threadIdx.x;
    int w = tid >> 6, lane = tid & 63;
    int wr = w >> 1, wc = w & 1;
    int g = lane >> 4, r = lane & 15;
    int bm = blockIdx.y * BM;
    int bn = blockIdx.x * 64;
    __shared__ __align__(16) u16 Ab[2][BM * BK];
    __shared__ __align__(16) u16 Bb[2][64 * BK];
    int srow = w * 16 + (lane >> 2);
    int scol = (lane & 3) * 8;
    auto stage = [&](int buf, int k0) {
#pragma unroll
        for (int i = 0; i < 2; ++i)
            gload_lds16(A + (size_t)(bm + i * 64 + srow) * K + k0 + scol,
                        &Ab[buf][(i * 64 + w * 16) * BK]);
        gload_lds16(W + (size_t)(bn + srow) * K + k0 + scol, &Bb[buf][w * 16 * BK]);
    };
    f32x4 acc[MF][2] = {};
    stage(0, 0);
    __syncthreads();
    for (int st = 0; st < NK; ++st) {
        int cur = st & 1;
        if (st + 1 < NK) stage(cur ^ 1, (st + 1) * BK);
        const u16* Al = &Ab[cur][0];
        const u16* Bl = &Bb[cur][0];
        bf16x8 bf[2];
#pragma unroll
        for (int u = 0; u < 2; ++u)
            bf[u] = *(const bf16x8*)(Bl + (wc * 32 + u * 16 + r) * BK + g * 8);
#pragma unroll
        for (int t = 0; t < MF; ++t) {
            bf16x8 af = *(const bf16x8*)(Al + (wr * 64 + t * 16 + r) * BK + g * 8);
#pragma unroll
            for (int u = 0; u < 2; ++u)
                acc[t][u] = __builtin_amdgcn_mfma_f32_16x16x32_bf16(af, bf[u], acc[t][u], 0, 0, 0);
        }
        __syncthreads();
    }
    constexpr float QS = 0.125f * 1.4426950408889634f;  // 1/sqrt(DH) * log2(e)
    int region = blockIdx.x >> 2;        // 0=q, 1=k, 2=v
    int head = blockIdx.x & 3;
    int r0 = bm + wr * 64 + g * 4;
    if (region == 2) {
#pragma unroll
        for (int t = 0; t < MF; ++t)
#pragma unroll
            for (int u = 0; u < 2; ++u) {
                int d = wc * 32 + u * 16 + r;
                int col = bn + d;
                ushort4 vo;
                vo.x = f2bf(acc[t][u][0] + bias[col]);
                vo.y = f2bf(acc[t][u][1] + bias[col]);
                vo.z = f2bf(acc[t][u][2] + bias[col]);
                vo.w = f2bf(acc[t][u][3] + bias[col]);
                *(ushort4*)(VTb + ((size_t)head * 64 + d) * kN + r0 + t * 16) = vo;
            }
    } else {
        u16* dst = (region == 0) ? Qb : Kb;
        float sc = (region == 0) ? QS : 1.f;
#pragma unroll
        for (int t = 0; t < MF; ++t)
#pragma unroll
            for (int u = 0; u < 2; ++u)
#pragma unroll
                for (int e = 0; e < 4; ++e) {
                    int d = wc * 32 + u * 16 + r;
                    int row = r0 + t * 16 + e;
                    dst[((size_t)head * kN + row) * 64 + d] =
                        f2bf((acc[t][u][e] + bias[bn + d]) * sc);
                }
    }
}

// ---------------- 128x128-tile staged GAT GEMM: xl half -> fp8, xr half -> bf16 ----
template <int K>
__global__ __launch_bounds__(256) void gemm_gat(
    const u16* __restrict__ A, const u16* __restrict__ W,
    u8* __restrict__ Cl, u16* __restrict__ Cr) {
    constexpr int BK = 32;
    constexpr int NK = K / BK;
    int tid = threadIdx.x;
    int w = tid >> 6, lane = tid & 63;
    int wr = w >> 1, wc = w & 1;
    int g = lane >> 4, r = lane & 15;
    int bm = blockIdx.y * 128;
    int bn = blockIdx.x * 128;
    __shared__ __align__(16) u16 Ab[2][128 * BK];
    __shared__ __align__(16) u16 Bb[2][128 * BK];
    int srd = lane >> 2;
    int schunk = ((lane & 3) ^ ((lane >> 3) & 3)) * 8;
    auto stage = [&](int buf, int k0) {
#pragma unroll
        for (int i = 0; i < 2; ++i) {
            int rowA = bm + i * 64 + w * 16 + srd;
            int rowB = bn + i * 64 + w * 16 + srd;
            gload_lds16(A + (size_t)rowA * K + k0 + schunk, &Ab[buf][(i * 64 + w * 16) * BK]);
            gload_lds16(W + (size_t)rowB * K + k0 + schunk, &Bb[buf][(i * 64 + w * 16) * BK]);
        }
    };
    f32x4 acc[4][4] = {};
    stage(0, 0);
    __syncthreads();
    int rs = (r >> 1) & 3;
    for (int st = 0; st < NK; ++st) {
        int cur = st & 1;
        if (st + 1 < NK) stage(cur ^ 1, (st + 1) * BK);
        const u16* Al = &Ab[cur][0];
        const u16* Bl = &Bb[cur][0];
        bf16x8 bf[4];
#pragma unroll
        for (int u = 0; u < 4; ++u)
            bf[u] = *(const bf16x8*)(Bl + (wc * 64 + u * 16 + r) * BK + ((g ^ rs) * 8));
#pragma unroll
        for (int t = 0; t < 4; ++t) {
            bf16x8 af = *(const bf16x8*)(Al + (wr * 64 + t * 16 + r) * BK + ((g ^ rs) * 8));
#pragma unroll
            for (int u = 0; u < 4; ++u)
                acc[t][u] = __builtin_amdgcn_mfma_f32_16x16x32_bf16(af, bf[u], acc[t][u], 0, 0, 0);
        }
        __syncthreads();
    }
    if (bn < 1024) {   // xl half -> fp8 e4m3
#pragma unroll
        for (int t = 0; t < 4; ++t)
#pragma unroll
            for (int u = 0; u < 4; ++u)
#pragma unroll
                for (int e = 0; e < 4; ++e) {
                    int row = bm + wr * 64 + t * 16 + g * 4 + e;
                    int col = bn + wc * 64 + u * 16 + r;
                    int pk = __builtin_amdgcn_cvt_pk_fp8_f32(acc[t][u][e], acc[t][u][e], 0, false);
                    Cl[(size_t)row * 1024 + col] = (u8)(pk & 0xff);
                }
    } else {           // xr half -> bf16
#pragma unroll
        for (int t = 0; t < 4; ++t)
#pragma unroll
            for (int u = 0; u < 4; ++u)
#pragma unroll
                for (int e = 0; e < 4; ++e) {
                    int row = bm + wr * 64 + t * 16 + g * 4 + e;
                    int col = (bn - 1024) + wc * 64 + u * 16 + r;
                    Cr[(size_t)row * 1024 + col] = f2bf(acc[t][u][e]);
                }
    }
}

// ---------------- GEMM (N=256) + fused bias + residual + LayerNorm ----------------
template <int BM, int K>
__global__ __launch_bounds__(256) void gemm_ln(
    const u16* __restrict__ A, const u16* __restrict__ W,
    const float* __restrict__ bias,
    const float* __restrict__ lng, const float* __restrict__ lnb,
    float* __restrict__ h, u16* __restrict__ hbf) {
    constexpr int BK = 32;
    constexpr int NK = K / BK;
    constexpr int MT = BM / 16;
    int tid = threadIdx.x;
    int w = tid >> 6, lane = tid & 63;
    int g = lane >> 4, r = lane & 15;
    int bm = blockIdx.x * BM;
    __shared__ __align__(16) u16 Ab[2][BM * BK];
    __shared__ __align__(16) u16 Bb[2][256 * BK];
    __shared__ float sums[BM][4][2];
    int srd = lane >> 2;
    int schunk = ((lane & 3) ^ ((lane >> 3) & 3)) * 8;
    auto stage = [&](int buf, int k0) {
        if (w < MT)
            gload_lds16(A + (size_t)(bm + w * 16 + srd) * K + k0 + schunk,
                        &Ab[buf][(w * 16) * BK]);
#pragma unroll
        for (int i = 0; i < 4; ++i)
            gload_lds16(W + (size_t)(w * 64 + i * 16 + srd) * K + k0 + schunk,
                        &Bb[buf][(w * 64 + i * 16) * BK]);
    };
    f32x4 acc[MT][4] = {};
    stage(0, 0);
    __syncthreads();
    int rs = (r >> 1) & 3;
    for (int st = 0; st < NK; ++st) {
        int cur = st & 1;
        if (st + 1 < NK) stage(cur ^ 1, (st + 1) * BK);
        const u16* Al = &Ab[cur][0];
        const u16* Bl = &Bb[cur][0];
        bf16x8 bf[4];
#pragma unroll
        for (int u = 0; u < 4; ++u)
            bf[u] = *(const bf16x8*)(Bl + (w * 64 + u * 16 + r) * BK + ((g ^ rs) * 8));
#pragma unroll
        for (int t = 0; t < MT; ++t) {
            bf16x8 af = *(const bf16x8*)(Al + (t * 16 + r) * BK + ((g ^ rs) * 8));
#pragma unroll
            for (int u = 0; u < 4; ++u)
                acc[t][u] = __builtin_amdgcn_mfma_f32_16x16x32_bf16(af, bf[u], acc[t][u], 0, 0, 0);
        }
        __syncthreads();
    }
    float val[MT][4][4];
#pragma unroll
    for (int t = 0; t < MT; ++t)
#pragma unroll
        for (int e = 0; e < 4; ++e) {
            int row = bm + t * 16 + g * 4 + e;
            float s1 = 0.f, s2 = 0.f;
#pragma unroll
            for (int u = 0; u < 4; ++u) {
                int col = w * 64 + u * 16 + r;
                float v = acc[t][u][e] + bias[col] + h[(size_t)row * kC + col];
                val[t][u][e] = v;
                s1 += v;
                s2 += v * v;
            }
            s1 = dpp_ror_add16(s1);
            s2 = dpp_ror_add16(s2);
            if (r == 0) {
                sums[t * 16 + g * 4 + e][w][0] = s1;
                sums[t * 16 + g * 4 + e][w][1] = s2;
            }
        }
    __syncthreads();
#pragma unroll
    for (int t = 0; t < MT; ++t)
#pragma unroll
        for (int e = 0; e < 4; ++e) {
            int lr = t * 16 + g * 4 + e;
            int row = bm + lr;
            float S1 = sums[lr][0][0] + sums[lr][1][0] + sums[lr][2][0] + sums[lr][3][0];
            float S2 = sums[lr][0][1] + sums[lr][1][1] + sums[lr][2][1] + sums[lr][3][1];
            float mu = S1 * (1.f / kC);
            float rstd = rsqrtf(S2 * (1.f / kC) - mu * mu + 1e-5f);
#pragma unroll
            for (int u = 0; u < 4; ++u) {
                int col = w * 64 + u * 16 + r;
                float y = (val[t][u][e] - mu) * rstd * lng[col] + lnb[col];
                h[(size_t)row * kC + col] = y;
                hbf[(size_t)row * kC + col] = f2bf(y);
            }
        }
}

// ---------------- GATv2: per-node online softmax aggregation + fused residual LN ----
// 8 edges in flight per wave: lane = (group gq = lane>>3, tt = lane&7); each
// 8-lane group owns one edge, 32 channels/lane. Score reduce = dpp_sum8
// (quad xor1 + xor2 + half_mirror). Exact 8-way LSE merge via shfl_xor 8/16/32.
__global__ __launch_bounds__(256) void gat_agg(
    const u8* __restrict__ xl8, const u16* __restrict__ xr16,
    const float* __restrict__ att, const float* __restrict__ gb,
    const int* __restrict__ off, const int* __restrict__ srcs,
    const float* __restrict__ lng, const float* __restrict__ lnb,
    float* __restrict__ h, u16* __restrict__ hbf) {
    int n = blockIdx.x;
    int w = threadIdx.x >> 6, lane = threadIdx.x & 63;
    int gq = lane >> 3, tt = lane & 7;
    int cb = w * 256 + tt * 32;   // channel slice [cb, cb+32) of 1024

    float xrv[32];
    {
        uint4 a0 = *(const uint4*)(xr16 + (size_t)n * 1024 + cb);
        uint4 a1 = *(const uint4*)(xr16 + (size_t)n * 1024 + cb + 8);
        uint4 a2 = *(const uint4*)(xr16 + (size_t)n * 1024 + cb + 16);
        uint4 a3 = *(const uint4*)(xr16 + (size_t)n * 1024 + cb + 24);
        unpack8(a0, xrv); unpack8(a1, xrv + 8); unpack8(a2, xrv + 16); unpack8(a3, xrv + 24);
    }
    float att6[32], att4[32];
#pragma unroll
    for (int j = 0; j < 32; j += 4) {
        float4 a4 = *(const float4*)(att + cb + j);
        att6[j] = 0.6f * a4.x; att6[j + 1] = 0.6f * a4.y;
        att6[j + 2] = 0.6f * a4.z; att6[j + 3] = 0.6f * a4.w;
        att4[j] = (2.f / 3.f) * att6[j]; att4[j + 1] = (2.f / 3.f) * att6[j + 1];
        att4[j + 2] = (2.f / 3.f) * att6[j + 2]; att4[j + 3] = (2.f / 3.f) * att6[j + 3];
    }

    int i0 = off[n], i1 = off[n + 1];
    float m = -1e30f, ls = 0.f;
    float acc[32] = {};
    int i = i0 + gq;
    uint4 pa0, pa1, pb0, pb1;
    if (i < i1) {
        const u8* sp = xl8 + (size_t)srcs[i] * 1024 + cb;
        pa0 = *(const uint4*)sp; pa1 = *(const uint4*)(sp + 16);
    }
    if (i + 8 < i1) {
        const u8* sp = xl8 + (size_t)srcs[i + 8] * 1024 + cb;
        pb0 = *(const uint4*)sp; pb1 = *(const uint4*)(sp + 16);
    }
    while (i < i1) {
        uint4 c0 = pa0, c1 = pa1;
        pa0 = pb0; pa1 = pb1;
        if (i + 16 < i1) {
            const u8* sp = xl8 + (size_t)srcs[i + 16] * 1024 + cb;
            pb0 = *(const uint4*)sp; pb1 = *(const uint4*)(sp + 16);
        }
        float x[32];
        unpack_fp8x4(c0.x, x);      unpack_fp8x4(c0.y, x + 4);
        unpack_fp8x4(c0.z, x + 8);  unpack_fp8x4(c0.w, x + 12);
        unpack_fp8x4(c1.x, x + 16); unpack_fp8x4(c1.y, x + 20);
        unpack_fp8x4(c1.z, x + 24); unpack_fp8x4(c1.w, x + 28);
        float p = 0.f;
#pragma unroll
        for (int j = 0; j < 32; ++j) {
            float e = x[j] + xrv[j];
            p = fmaf(att6[j], e, p);
            p = fmaf(att4[j], __builtin_fabsf(e), p);
        }
        p = dpp_sum8(p);        // all 8 lanes of the group now hold the score
        if (p > m) {            // group-uniform
            float c = __expf(m - p);
            ls = ls * c + 1.f;
#pragma unroll
            for (int j = 0; j < 32; ++j) acc[j] = acc[j] * c + x[j];
            m = p;
        } else {
            float pw = __expf(p - m);
            ls += pw;
#pragma unroll
            for (int j = 0; j < 32; ++j) acc[j] = fmaf(pw, x[j], acc[j]);
        }
        i += 8;
    }
    // exact LSE merge of the 8 group states (group index = lane bits 3..5)
    float mm = fmaxf(m, __shfl_xor(m, 8));
    mm = fmaxf(mm, __shfl_xor(mm, 16));
    mm = fmaxf(mm, __shfl_xor(mm, 32));
    float c = __expf(m - mm);   // 0 for empty groups (m = -1e30; self-loop guarantees >=1 edge)
    ls *= c;
    ls += __shfl_xor(ls, 8);
    ls += __shfl_xor(ls, 16);
    ls += __shfl_xor(ls, 32);
#pragma unroll
    for (int j = 0; j < 32; ++j) {
        float a = acc[j] * c;
        a += __shfl_xor(a, 8);
        a += __shfl_xor(a, 16);
        a += __shfl_xor(a, 32);
        acc[j] = a;
    }
    float inv = 1.f / ls;
    __shared__ float red[4][256];
    __shared__ float rs[8];
    if (gq == 0) {
#pragma unroll
        for (int j = 0; j < 32; ++j) red[w][tt * 32 + j] = acc[j] * inv;
    }
    __syncthreads();
    int cc = threadIdx.x;
    float vsum = 0.25f * (red[0][cc] + red[1][cc] + red[2][cc] + red[3][cc]) + gb[cc];
    float v = h[(size_t)n * kC + cc] + vsum;
    float s1 = v, s2 = v * v;
    for (int d = 1; d < 64; d <<= 1) { s1 += __shfl_xor(s1, d); s2 += __shfl_xor(s2, d); }
    if (lane == 0) { rs[w] = s1; rs[4 + w] = s2; }
    __syncthreads();
    s1 = rs[0] + rs[1] + rs[2] + rs[3];
    s2 = rs[4] + rs[5] + rs[6] + rs[7];
    float mu = s1 * (1.f / kC);
    float rstd = rsqrtf(s2 * (1.f / kC) - mu * mu + 1e-5f);
    float y = (v - mu) * rstd * lng[cc] + lnb[cc];
    h[(size_t)n * kC + cc] = y;
    hbf[(size_t)n * kC + cc] = f2bf(y);
}

// ---------------- MFMA flash attention: 128 q-rows/block, time-shared plds --------
// NSPLIT=8 -> grid 1024 blocks = 4 blocks/CU (matches 40KB LDS capacity).
__global__ __launch_bounds__(256, 4) void mha_mfma3(
    const u16* __restrict__ Qb, const u16* __restrict__ Kb,
    const u16* __restrict__ VTb, u16* __restrict__ opart, float* __restrict__ mlpart) {
    int qt = blockIdx.x, head = blockIdx.y, sp = blockIdx.z;
    int tid = threadIdx.x;
    int w = tid >> 6, lane = tid & 63;
    int g = lane >> 4, r = lane & 15;
    int q0 = qt * 128;
    const u16* QhA = Qb + ((size_t)head * kN + q0 + w * 16) * 64;
    const u16* QhB = QhA + (size_t)64 * 64;
    const u16* Kh = Kb + (size_t)head * kN * 64;
    const u16* VTh = VTb + (size_t)head * 64 * kN;
    __shared__ u16 Kt[2][64 * 64];
    __shared__ u16 Vt[2][64 * 64];
    __shared__ u16 plds[4][16 * 64];
    int srow = w * 8 + (lane >> 3);
    int schunk = ((lane & 7) ^ ((lane >> 3) & 7)) * 8;
    int kbase = sp * KSPAN;

    bf16x8 qfA0 = *(const bf16x8*)(QhA + r * 64 + g * 8);
    bf16x8 qfA1 = *(const bf16x8*)(QhA + r * 64 + 32 + g * 8);
    bf16x8 qfB0 = *(const bf16x8*)(QhB + r * 64 + g * 8);
    bf16x8 qfB1 = *(const bf16x8*)(QhB + r * 64 + 32 + g * 8);

    auto stage = [&](int buf, int k0) {
#pragma unroll
        for (int i = 0; i < 2; ++i) {
            int row = i * 32 + srow;
            gload_lds16(Kh + (size_t)(k0 + row) * 64 + schunk, &Kt[buf][(i * 32 + w * 8) * 64]);
            gload_lds16(VTh + (size_t)row * kN + k0 + schunk, &Vt[buf][(i * 32 + w * 8) * 64]);
        }
    };

    f32x4 oA[4] = {}, oB[4] = {};
    float mA = -3.0e38f, lA = 0.f, mB = -3.0e38f, lB = 0.f;

    stage(0, kbase);
    __syncthreads();

    int rx = r & 7;
    for (int st = 0; st < NSTEP; ++st) {
        int cur = st & 1;
        if (st + 1 < NSTEP) stage(cur ^ 1, kbase + (st + 1) * 64);
        const u16* Kl = &Kt[cur][0];
        const u16* Vl = &Vt[cur][0];
        bf16x8 paA0, paA1;
        // ---- set A: QK^T, softmax, P->plds, pull PA frags into regs ----
        {
            f32x4 stt[4] = {};
#pragma unroll
            for (int t = 0; t < 4; ++t) {
                bf16x8 kf0 = *(const bf16x8*)(Kl + (16 * t + r) * 64 + ((0 + g) ^ rx) * 8);
                bf16x8 kf1 = *(const bf16x8*)(Kl + (16 * t + r) * 64 + ((4 + g) ^ rx) * 8);
                stt[t] = __builtin_amdgcn_mfma_f32_16x16x32_bf16(kf0, qfA0, stt[t], 0, 0, 0);
                stt[t] = __builtin_amdgcn_mfma_f32_16x16x32_bf16(kf1, qfA1, stt[t], 0, 0, 0);
            }
            float pm = stt[0][0];
#pragma unroll
            for (int t = 0; t < 4; ++t)
#pragma unroll
                for (int e = 0; e < 4; ++e) pm = fmaxf(pm, stt[t][e]);
            pm = fmaxf(pm, __shfl_xor(pm, 16));
            pm = fmaxf(pm, __shfl_xor(pm, 32));
            if (__any(pm > mA)) {
                float mn = fmaxf(mA, pm);
                float corr = __builtin_amdgcn_exp2f(mA - mn);
                lA *= corr;
                float corrq[4];
#pragma unroll
                for (int e = 0; e < 4; ++e) corrq[e] = __shfl(corr, g * 4 + e);
#pragma unroll
                for (int dt = 0; dt < 4; ++dt)
#pragma unroll
                    for (int e = 0; e < 4; ++e) oA[dt][e] *= corrq[e];
                mA = mn;
            }
            float lsx = 0.f;
#pragma unroll
            for (int t = 0; t < 4; ++t) {
                ushort4 pk;
                float p0 = __builtin_amdgcn_exp2f(stt[t][0] - mA);
                float p1 = __builtin_amdgcn_exp2f(stt[t][1] - mA);
                float p2 = __builtin_amdgcn_exp2f(stt[t][2] - mA);
                float p3 = __builtin_amdgcn_exp2f(stt[t][3] - mA);
                lsx += (p0 + p1) + (p2 + p3);
                pk.x = f2bf(p0); pk.y = f2bf(p1); pk.z = f2bf(p2); pk.w = f2bf(p3);
                int lc = (2 * t + (g >> 1)) ^ rx;
                *(ushort4*)(&plds[w][r * 64 + lc * 8 + (g & 1) * 4]) = pk;
            }
            lsx += __shfl_xor(lsx, 16);
            lsx += __shfl_xor(lsx, 32);
            lA += lsx;
            paA0 = *(const bf16x8*)(&plds[w][r * 64 + (g ^ rx) * 8]);
            paA1 = *(const bf16x8*)(&plds[w][r * 64 + ((4 + g) ^ rx) * 8]);
        }
        // ---- set B: QK^T, softmax, P->plds (reuses buffer after paA reads) ----
        {
            f32x4 stt[4] = {};
#pragma unroll
            for (int t = 0; t < 4; ++t) {
                bf16x8 kf0 = *(const bf16x8*)(Kl + (16 * t + r) * 64 + ((0 + g) ^ rx) * 8);
                bf16x8 kf1 = *(const bf16x8*)(Kl + (16 * t + r) * 64 + ((4 + g) ^ rx) * 8);
                stt[t] = __builtin_amdgcn_mfma_f32_16x16x32_bf16(kf0, qfB0, stt[t], 0, 0, 0);
                stt[t] = __builtin_amdgcn_mfma_f32_16x16x32_bf16(kf1, qfB1, stt[t], 0, 0, 0);
            }
            float pm = stt[0][0];
#pragma unroll
            for (int t = 0; t < 4; ++t)
#pragma unroll
                for (int e = 0; e < 4; ++e) pm = fmaxf(pm, stt[t][e]);
            pm = fmaxf(pm, __shfl_xor(pm, 16));
            pm = fmaxf(pm, __shfl_xor(pm, 32));
            if (__any(pm > mB)) {
                float mn = fmaxf(mB, pm);
                float corr = __builtin_amdgcn_exp2f(mB - mn);
                lB *= corr;
                float corrq[4];
#pragma unroll
                for (int e = 0; e < 4; ++e) corrq[e] = __shfl(corr, g * 4 + e);
#pragma unroll
                for (int dt = 0; dt < 4; ++dt)
#pragma unroll
                    for (int e = 0; e < 4; ++e) oB[dt][e] *= corrq[e];
                mB = mn;
            }
            float lsx = 0.f;
#pragma unroll
            for (int t = 0; t < 4; ++t) {
                ushort4 pk;
                float p0 = __builtin_amdgcn_exp2f(stt[t][0] - mB);
                float p1 = __builtin_amdgcn_exp2f(stt[t][1] - mB);
                float p2 = __builtin_amdgcn_exp2f(stt[t][2] - mB);
                float p3 = __builtin_amdgcn_exp2f(stt[t][3] - mB);
                lsx += (p0 + p1) + (p2 + p3);
                pk.x = f2bf(p0); pk.y = f2bf(p1); pk.z = f2bf(p2); pk.w = f2bf(p3);
                int lc = (2 * t + (g >> 1)) ^ rx;
                *(ushort4*)(&plds[w][r * 64 + lc * 8 + (g & 1) * 4]) = pk;
            }
            lsx += __shfl_xor(lsx, 16);
            lsx += __shfl_xor(lsx, 32);
            lB += lsx;
        }
        bf16x8 paB0 = *(const bf16x8*)(&plds[w][r * 64 + (g ^ rx) * 8]);
        bf16x8 paB1 = *(const bf16x8*)(&plds[w][r * 64 + ((4 + g) ^ rx) * 8]);
        // ---- PV: vf reads shared across both sets ----
#pragma unroll
        for (int dt = 0; dt < 4; ++dt) {
            bf16x8 vf0 = *(const bf16x8*)(Vl + (dt * 16 + r) * 64 + ((0 + g) ^ rx) * 8);
            bf16x8 vf1 = *(const bf16x8*)(Vl + (dt * 16 + r) * 64 + ((4 + g) ^ rx) * 8);
            oA[dt] = __builtin_amdgcn_mfma_f32_16x16x32_bf16(paA0, vf0, oA[dt], 0, 0, 0);
            oA[dt] = __builtin_amdgcn_mfma_f32_16x16x32_bf16(paA1, vf1, oA[dt], 0, 0, 0);
            oB[dt] = __builtin_amdgcn_mfma_f32_16x16x32_bf16(paB0, vf0, oB[dt], 0, 0, 0);
            oB[dt] = __builtin_amdgcn_mfma_f32_16x16x32_bf16(paB1, vf1, oB[dt], 0, 0, 0);
        }
        __syncthreads();
    }

    size_t slot = (size_t)(head * 32 + qt) * NSPLIT + sp;
    u16* ob = opart + slot * 8192;
#pragma unroll
    for (int dt = 0; dt < 4; ++dt)
#pragma unroll
        for (int e = 0; e < 4; ++e) {
            ob[(w * 16 + g * 4 + e) * 64 + dt * 16 + r] = f2bf(oA[dt][e]);
            ob[(64 + w * 16 + g * 4 + e) * 64 + dt * 16 + r] = f2bf(oB[dt][e]);
        }
    float* mlb = mlpart + slot * 256;
    if (g == 0) {
        mlb[w * 16 + r] = mA;
        mlb[64 + w * 16 + r] = mB;
        mlb[128 + w * 16 + r] = lA;
        mlb[192 + w * 16 + r] = lB;
    }
}

// ---------------- merge split-K attention partials -> attnb (bf16) ----------------
__global__ __launch_bounds__(256) void mha_merge(
    const u16* __restrict__ opart, const float* __restrict__ mlpart,
    u16* __restrict__ attnb) {
    int head = blockIdx.y;
    int q = blockIdx.x * 4 + (threadIdx.x >> 6);
    int d = threadIdx.x & 63;
    int qt = q >> 7, ql = q & 127;
    size_t sb = (size_t)(head * 32 + qt) * NSPLIT;
    float ms[NSPLIT], lsv[NSPLIT];
    float mstar = -3.0e38f;
#pragma unroll
    for (int s = 0; s < NSPLIT; ++s) {
        ms[s] = mlpart[(sb + s) * 256 + ql];
        lsv[s] = mlpart[(sb + s) * 256 + 128 + ql];
        mstar = fmaxf(mstar, ms[s]);
    }
    float acc = 0.f, lsum = 0.f;
#pragma unroll
    for (int s = 0; s < NSPLIT; ++s) {
        float wgt = __builtin_amdgcn_exp2f(ms[s] - mstar);
        lsum += lsv[s] * wgt;
        acc += bf2f(opart[(sb + s) * 8192 + ql * 64 + d]) * wgt;
    }
    attnb[(size_t)q * kC + head * 64 + d] = f2bf(acc / lsum);
}

// ---------------- final: out[4096,2] = t_bf @ out_w2^T + b2; wave per row ----------------
__global__ __launch_bounds__(256) void final_out(
    const u16* __restrict__ tbf, const float* __restrict__ w2,
    const float* __restrict__ b2, float* __restrict__ out) {
    int row = blockIdx.x * 4 + (threadIdx.x >> 6);
    int lane = threadIdx.x & 63;
    const ushort4 tv = *(const ushort4*)(tbf + (size_t)row * 256 + lane * 4);
    float t0 = bf2f(tv.x), t1 = bf2f(tv.y), t2 = bf2f(tv.z), t3 = bf2f(tv.w);
    const float4 w0 = *(const float4*)(w2 + lane * 4);
    const float4 w1 = *(const float4*)(w2 + 256 + lane * 4);
    float d0 = t0 * w0.x + t1 * w0.y + t2 * w0.z + t3 * w0.w;
    float d1 = t0 * w1.x + t1 * w1.y + t2 * w1.z + t3 * w1.w;
    for (int d = 1; d < 64; d <<= 1) { d0 += __shfl_xor(d0, d); d1 += __shfl_xor(d1, d); }
    if (lane == 0) {
        out[(size_t)row * 2 + 0] = d0 + b2[0];
        out[(size_t)row * 2 + 1] = d1 + b2[1];
    }
}

extern "C" void kernel_launch(void* const* d_in, const int* in_sizes, int n_in,
                              void* d_out, int out_size, void* d_ws, size_t ws_size,
                              hipStream_t stream) {
    (void)in_sizes; (void)n_in; (void)out_size;
    const float* x        = (const float*)d_in[0];
    const int*   ei       = (const int*)d_in[1];
    const float* in_w     = (const float*)d_in[2];
    const float* in_b     = (const float*)d_in[3];
    const float* gat_wl   = (const float*)d_in[4];
    const float* gat_wr   = (const float*)d_in[5];
    const float* gat_att  = (const float*)d_in[6];
    const float* gat_b    = (const float*)d_in[7];
    const float* mha_in_w = (const float*)d_in[8];
    const float* mha_in_b = (const float*)d_in[9];
    const float* mha_out_w= (const float*)d_in[10];
    const float* mha_out_b= (const float*)d_in[11];
    const float* ln1_g = (const float*)d_in[12];
    const float* ln1_b = (const float*)d_in[13];
    const float* ln2_g = (const float*)d_in[14];
    const float* ln2_b = (const float*)d_in[15];
    const float* ln3_g = (const float*)d_in[16];
    const float* ln3_b = (const float*)d_in[17];
    const float* ffn_w1 = (const float*)d_in[18];
    const float* ffn_b1 = (const float*)d_in[19];
    const float* ffn_w2 = (const float*)d_in[20];
    const float* ffn_b2 = (const float*)d_in[21];
    const float* out_w1 = (const float*)d_in[22];
    const float* out_b1 = (const float*)d_in[23];
    const float* out_w2 = (const float*)d_in[24];
    const float* out_b2 = (const float*)d_in[25];
    float* out = (float*)d_out;

    char* ws = (char*)d_ws;
    size_t off = 0;
    auto alloc = [&](size_t bytes) -> void* {
        void* p = (void*)(ws + off);
        off += (bytes + 255) & ~(size_t)255;
        return p;
    };
    float* h     = (float*)alloc((size_t)kN * kC * 4);
    u16*   hbf   = (u16*)  alloc((size_t)kN * kC * 2);
    float* xlb   = (float*)alloc((size_t)kN * 1024 * 4);   // slot reused: xl8+xr16 / Qb+Kb+VTb
    float* xrb   = (float*)alloc((size_t)kN * 1024 * 4);   // slot reused: opart (bf16, 16 MB)
    float* locb  = (float*)alloc((size_t)kN * kC * 4);     // slot reused: mlpart (1 MB)
    u16*   attnb = (u16*)  alloc((size_t)kN * kC * 2);
    u16*   midb  = (u16*)  alloc((size_t)kN * 512 * 2);
    u16*   tbf   = (u16*)  alloc((size_t)kN * kC * 2);
    u16*   xbf   = (u16*)  alloc((size_t)kN * kIn * 2);
    u16*   wbf   = (u16*)  alloc((size_t)3342336 * 2);
    int*   coff  = (int*)  alloc((size_t)4097 * 4);
    int*   ccur  = (int*)  alloc((size_t)4096 * 4);
    int*   csrc  = (int*)  alloc((size_t)kET * 4);
    if (ws_size < off) return;  // not enough scratch: bail loudly (output stays poisoned)

    // GAT transform outputs: xl in fp8 (4 MB, gathered, ~L2-resident), xr in bf16 (8 MB).
    u8*  xl8  = (u8*)xlb;                        // [4096][1024] fp8
    u16* xr16 = (u16*)((char*)xlb + (size_t)kN * 1024);  // [4096][1024] bf16
    // MHA operands alias the same 16 MB slot (xl8/xr16 dead after gat_agg).
    u16* Qb  = (u16*)xlb;                        // [4][4096][64]
    u16* Kb  = Qb + (size_t)4 * kN * 64;         // [4][4096][64]
    u16* VTb = Kb + (size_t)4 * kN * 64;         // [4][64][4096]
    u16*   opart  = (u16*)xrb;                   // 1024 slots x 8192 bf16 = 16 MB exact
    float* mlpart = locb;                        // 1024 x 256 f32 = 1 MB

    // bf16 weight buffer offsets (elements); gat wl/wr interleaved per layer [2048][256]
    const size_t OFF_INW  = 0;
    const size_t OFF_GAT  = 131072;
    const size_t OFF_MIN  = 1703936;
    const size_t OFF_MOUT = 2293760;
    const size_t OFF_F1   = 2490368;
    const size_t OFF_F2   = 2883584;
    const size_t OFF_O1   = 3276800;

    // CSR count is fused into cast_all -> zero the counters first
    hipMemsetAsync(ccur, 0, 4096 * 4, stream);
    cast_all<<<dim3(1495040 / 256), dim3(256), 0, stream>>>(
        x, in_w, gat_wl, gat_wr, mha_in_w, mha_out_w, ffn_w1, ffn_w2, out_w1,
        xbf, wbf, ei, ccur);
    csr_scan<<<dim3(1), dim3(1024), 0, stream>>>(ccur, coff);
    csr_scatter<<<dim3((kET + 255) / 256), dim3(256), 0, stream>>>(ei, ccur, csrc);

    // input projection: h = x @ in_w^T + in_b  (fp32 + bf16 outputs)
    gemm_st<64, 512, 0, 1, 1><<<dim3(kC / 64, kN / 64), dim3(256), 0, stream>>>(
        xbf, wbf + OFF_INW, in_b, h, hbf, kC);

    for (int l = 0; l < kL; ++l) {
        // GATv2 transforms: fused wl|wr 128x128-tile GEMM -> xl8 (fp8) + xr16 (bf16)
        gemm_gat<256><<<dim3(2048 / 128, kN / 128), dim3(256), 0, stream>>>(
            hbf, wbf + OFF_GAT + (size_t)l * 524288, xl8, xr16);
        // gat_agg with fused residual + ln1 (writes h, hbf directly)
        gat_agg<<<dim3(kN), dim3(256), 0, stream>>>(
            xl8, xr16, gat_att + (size_t)l * 1024, gat_b + (size_t)l * kC, coff, csrc,
            ln1_g + (size_t)l * kC, ln1_b + (size_t)l * kC, h, hbf);

        // MHA: fused qkv GEMM writes Qb/Kb/VTb directly
        gemm_qkv<<<dim3(768 / 64, kN / 128), dim3(256), 0, stream>>>(
            hbf, wbf + OFF_MIN + (size_t)l * 768 * kC, mha_in_b + (size_t)l * 768,
            Qb, Kb, VTb);
        mha_mfma3<<<dim3(kN / 128, 4, NSPLIT), dim3(256), 0, stream>>>(Qb, Kb, VTb, opart, mlpart);
        mha_merge<<<dim3(kN / 4, 4), dim3(256), 0, stream>>>(opart, mlpart, attnb);
        // mout GEMM + fused residual + ln2
        gemm_ln<16, 256><<<dim3(kN / 16), dim3(256), 0, stream>>>(
            attnb, wbf + OFF_MOUT + (size_t)l * kC * kC, mha_out_b + (size_t)l * kC,
            ln2_g + (size_t)l * kC, ln2_b + (size_t)l * kC, h, hbf);

        // FFN: ffn1 GEMM (+gelu) then ffn2 GEMM + fused residual + ln3
        gemm_st<64, 256, 1, 0, 1><<<dim3(512 / 64, kN / 64), dim3(256), 0, stream>>>(
            hbf, wbf + OFF_F1 + (size_t)l * 512 * kC, ffn_b1 + (size_t)l * 512, nullptr, midb, 512);
        gemm_ln<16, 512><<<dim3(kN / 16), dim3(256), 0, stream>>>(
            midb, wbf + OFF_F2 + (size_t)l * kC * 512, ffn_b2 + (size_t)l * kC,
            ln3_g + (size_t)l * kC, ln3_b + (size_t)l * kC, h, hbf);
    }

    // output head
    gemm_st<64, 256, 1, 0, 1><<<dim3(kC / 64, kN / 64), dim3(256), 0, stream>>>(
        hbf, wbf + OFF_O1, out_b1, nullptr, tbf, kC);
    final_out<<<dim3(kN / 4), dim3(256), 0, stream>>>(tbf, out_w2, out_b2, out);
}

// Round 21
// 452.351 us; speedup vs baseline: 1.1907x; 1.1907x over previous
//
#include <hip/hip_runtime.h>
#include <cstdint>
#include <cstddef>

typedef unsigned short u16;
typedef unsigned char u8;
typedef __bf16 bf16x8 __attribute__((ext_vector_type(8)));
typedef float f32x4 __attribute__((ext_vector_type(4)));
typedef float f32x2 __attribute__((ext_vector_type(2)));

constexpr int kN  = 4096;
constexpr int kE  = 131072;
constexpr int kET = kE + kN;   // with self loops
constexpr int kIn = 512;
constexpr int kC  = 256;
constexpr int kL  = 3;

constexpr int NSPLIT = 8;
constexpr int KSPAN  = kN / NSPLIT;  // 512 keys per split
constexpr int NSTEP  = KSPAN / 64;   // 8 steps of 64 keys

__device__ __forceinline__ u16 f2bf(float f) {
    unsigned u = __builtin_bit_cast(unsigned, f);
    u += 0x7fffu + ((u >> 16) & 1u);
    return (u16)(u >> 16);
}
__device__ __forceinline__ float bf2f(u16 s) {
    unsigned u = ((unsigned)s) << 16;
    return __builtin_bit_cast(float, u);
}
__device__ __forceinline__ float gelu_erf(float x) {
    return 0.5f * x * (1.f + erff(x * 0.70710678118654752f));
}
// async global->LDS, 16B per lane; ldst must be wave-uniform base (HW adds lane*16)
__device__ __forceinline__ void gload_lds16(const u16* gsrc, u16* ldst) {
    __builtin_amdgcn_global_load_lds(
        (const __attribute__((address_space(1))) unsigned int*)gsrc,
        (__attribute__((address_space(3))) unsigned int*)ldst, 16, 0, 0);
}
// sum over each row of 16 lanes via DPP row_ror adds (full-rate VALU, no LDS pipe)
__device__ __forceinline__ float dpp_ror_add16(float x) {
    int t;
    t = __builtin_amdgcn_update_dpp(0, __builtin_bit_cast(int, x), 0x121, 0xf, 0xf, true);
    x += __builtin_bit_cast(float, t);
    t = __builtin_amdgcn_update_dpp(0, __builtin_bit_cast(int, x), 0x122, 0xf, 0xf, true);
    x += __builtin_bit_cast(float, t);
    t = __builtin_amdgcn_update_dpp(0, __builtin_bit_cast(int, x), 0x124, 0xf, 0xf, true);
    x += __builtin_bit_cast(float, t);
    t = __builtin_amdgcn_update_dpp(0, __builtin_bit_cast(int, x), 0x128, 0xf, 0xf, true);
    x += __builtin_bit_cast(float, t);
    return x;
}
// unpack 8 bf16 (uint4) -> 8 f32
__device__ __forceinline__ void unpack8(uint4 u, float* x) {
    x[0] = __builtin_bit_cast(float, u.x << 16);
    x[1] = __builtin_bit_cast(float, u.x & 0xffff0000u);
    x[2] = __builtin_bit_cast(float, u.y << 16);
    x[3] = __builtin_bit_cast(float, u.y & 0xffff0000u);
    x[4] = __builtin_bit_cast(float, u.z << 16);
    x[5] = __builtin_bit_cast(float, u.z & 0xffff0000u);
    x[6] = __builtin_bit_cast(float, u.w << 16);
    x[7] = __builtin_bit_cast(float, u.w & 0xffff0000u);
}
// unpack 4 fp8(e4m3) packed in a u32 -> 4 f32
__device__ __forceinline__ void unpack_fp8x4(unsigned wv, float* x) {
    f32x2 lo = __builtin_amdgcn_cvt_pk_f32_fp8(wv, false);
    f32x2 hi = __builtin_amdgcn_cvt_pk_f32_fp8(wv, true);
    x[0] = lo[0]; x[1] = lo[1]; x[2] = hi[0]; x[3] = hi[1];
}

// ---------------- fused fp32->bf16 cast of ALL weights + x + csr_count ------------
__global__ void cast_all(
    const float* __restrict__ x, const float* __restrict__ in_w,
    const float* __restrict__ gwl, const float* __restrict__ gwr,
    const float* __restrict__ minw, const float* __restrict__ moutw,
    const float* __restrict__ f1, const float* __restrict__ f2,
    const float* __restrict__ o1,
    u16* __restrict__ xbf, u16* __restrict__ wbf,
    const int* __restrict__ ei, int* __restrict__ cnt) {
    int i = blockIdx.x * 256 + threadIdx.x;
    if (i >= 1495040) return;
    if (i >= 1359872) {                     // csr_count region (kET edges)
        int e = i - 1359872;
        int d = (e < kE) ? ei[kE + e] : (e - kE);
        atomicAdd(cnt + d, 1);
        return;
    }
    const float* s;
    u16* dbase;
    int sj, dj;
    if (i < 524288) {                       // x: 4096x512
        s = x; dbase = xbf; sj = i; dj = i;
    } else if (i < 557056) {                // in_w
        s = in_w; dbase = wbf; sj = i - 524288; dj = sj;
    } else if (i < 753664) {                // gat_wl (interleaved)
        int j = i - 557056; int l = j >> 16, wi = j & 65535;
        s = gwl; dbase = wbf; sj = j; dj = 32768 + l * 131072 + wi;
    } else if (i < 950272) {                // gat_wr (interleaved, +65536)
        int j = i - 753664; int l = j >> 16, wi = j & 65535;
        s = gwr; dbase = wbf; sj = j; dj = 32768 + l * 131072 + 65536 + wi;
    } else if (i < 1097728) {               // mha_in_w
        s = minw; dbase = wbf; sj = i - 950272; dj = 425984 + sj;
    } else if (i < 1146880) {               // mha_out_w
        s = moutw; dbase = wbf; sj = i - 1097728; dj = 573440 + sj;
    } else if (i < 1245184) {               // ffn_w1
        s = f1; dbase = wbf; sj = i - 1146880; dj = 622592 + sj;
    } else if (i < 1343488) {               // ffn_w2
        s = f2; dbase = wbf; sj = i - 1245184; dj = 720896 + sj;
    } else {                                // out_w1
        s = o1; dbase = wbf; sj = i - 1343488; dj = 819200 + sj;
    }
    float4 v = ((const float4*)s)[sj];
    ushort4 o;
    o.x = f2bf(v.x); o.y = f2bf(v.y); o.z = f2bf(v.z); o.w = f2bf(v.w);
    ((ushort4*)dbase)[dj] = o;
}

// ---------------- CSR scan + scatter ----------------
__global__ __launch_bounds__(1024) void csr_scan(int* __restrict__ cnt_cur, int* __restrict__ off) {
    __shared__ int lds[1024];
    int t = threadIdx.x;
    int c[4], s = 0;
#pragma unroll
    for (int j = 0; j < 4; ++j) { c[j] = cnt_cur[t * 4 + j]; s += c[j]; }
    lds[t] = s;
    __syncthreads();
    for (int d = 1; d < 1024; d <<= 1) {
        int v = (t >= d) ? lds[t - d] : 0;
        __syncthreads();
        lds[t] += v;
        __syncthreads();
    }
    int excl = lds[t] - s;
#pragma unroll
    for (int j = 0; j < 4; ++j) { off[t * 4 + j] = excl; cnt_cur[t * 4 + j] = excl; excl += c[j]; }
    if (t == 1023) off[4096] = excl;
}

__global__ void csr_scatter(const int* __restrict__ ei, int* __restrict__ cur, int* __restrict__ csrc) {
    int e = blockIdx.x * 256 + threadIdx.x;
    if (e >= kET) return;
    int s, d;
    if (e < kE) { s = ei[e]; d = ei[kE + e]; } else { s = d = e - kE; }
    int pos = atomicAdd(cur + d, 1);
    csrc[pos] = s;
}

// ---------------- staged bf16 MFMA GEMM: C[M,N] = act(A[M,K] @ W[N,K]^T + bias) ----
template <int BM, int K, int ACT, int WF32, int WBF16>
__global__ __launch_bounds__(256) void gemm_st(
    const u16* __restrict__ A, const u16* __restrict__ W,
    const float* __restrict__ bias, float* __restrict__ Cf,
    u16* __restrict__ Cb, int N) {
    constexpr int BK = 32;
    constexpr int NK = K / BK;
    constexpr int MF = BM / 32;          // A fragments per wave
    int tid = threadIdx.x;
    int w = tid >> 6, lane = tid & 63;
    int wr = w >> 1, wc = w & 1;
    int g = lane >> 4, r = lane & 15;
    int bm = blockIdx.y * BM;
    int bn = blockIdx.x * 64;
    __shared__ __align__(16) u16 Ab[2][BM * BK];
    __shared__ __align__(16) u16 Bb[2][64 * BK];
    int srow = w * 16 + (lane >> 2);
    int scol = (lane & 3) * 8;
    auto stage = [&](int buf, int k0) {
#pragma unroll
        for (int i = 0; i < BM / 64; ++i)
            gload_lds16(A + (size_t)(bm + i * 64 + srow) * K + k0 + scol,
                        &Ab[buf][(i * 64 + w * 16) * BK]);
        gload_lds16(W + (size_t)(bn + srow) * K + k0 + scol, &Bb[buf][w * 16 * BK]);
    };
    f32x4 acc[MF][2] = {};
    stage(0, 0);
    __syncthreads();
    for (int st = 0; st < NK; ++st) {
        int cur = st & 1;
        if (st + 1 < NK) stage(cur ^ 1, (st + 1) * BK);
        const u16* Al = &Ab[cur][0];
        const u16* Bl = &Bb[cur][0];
        bf16x8 bf[2];
#pragma unroll
        for (int u = 0; u < 2; ++u)
            bf[u] = *(const bf16x8*)(Bl + (wc * 32 + u * 16 + r) * BK + g * 8);
#pragma unroll
        for (int t = 0; t < MF; ++t) {
            bf16x8 af = *(const bf16x8*)(Al + (wr * (BM / 2) + t * 16 + r) * BK + g * 8);
#pragma unroll
            for (int u = 0; u < 2; ++u)
                acc[t][u] = __builtin_amdgcn_mfma_f32_16x16x32_bf16(af, bf[u], acc[t][u], 0, 0, 0);
        }
        __syncthreads();
    }
    int r0 = bm + wr * (BM / 2) + g * 4;
    int c0 = bn + wc * 32 + r;
#pragma unroll
    for (int t = 0; t < MF; ++t)
#pragma unroll
        for (int u = 0; u < 2; ++u)
#pragma unroll
            for (int e = 0; e < 4; ++e) {
                int row = r0 + t * 16 + e, col = c0 + u * 16;
                float v = acc[t][u][e];
                if (bias) v += bias[col];
                if (ACT == 1) v = gelu_erf(v);
                if (WF32) Cf[(size_t)row * N + col] = v;
                if (WBF16) Cb[(size_t)row * N + col] = f2bf(v);
            }
}

// ---------------- fused qkv GEMM: writes Qb/Kb [head][n][64] and VTb [head][d][n] ---
__global__ __launch_bounds__(256) void gemm_qkv(
    const u16* __restrict__ A, const u16* __restrict__ W,
    const float* __restrict__ bias,
    u16* __restrict__ Qb, u16* __restrict__ Kb, u16* __restrict__ VTb) {
    constexpr int BK = 32, K = 256, NK = 8, BM = 128, MF = 4;
    int tid = threadIdx.x;
    int w = tid >> 6, lane = tid & 63;
    int wr = w >> 1, wc = w & 1;
    int g = lane >> 4, r = lane & 15;
    int bm = blockIdx.y * BM;
    int bn = blockIdx.x * 64;
    __shared__ __align__(16) u16 Ab[2][BM * BK];
    __shared__ __align__(16) u16 Bb[2][64 * BK];
    int srow = w * 16 + (lane >> 2);
    int scol = (lane & 3) * 8;
    auto stage = [&](int buf, int k0) {
#pragma unroll
        for (int i = 0; i < 2; ++i)
            gload_lds16(A + (size_t)(bm + i * 64 + srow) * K + k0 + scol,
                        &Ab[buf][(i * 64 + w * 16) * BK]);
        gload_lds16(W + (size_t)(bn + srow) * K + k0 + scol, &Bb[buf][w * 16 * BK]);
    };
    f32x4 acc[MF][2] = {};
    stage(0, 0);
    __syncthreads();
    for (int st = 0; st < NK; ++st) {
        int cur = st & 1;
        if (st + 1 < NK) stage(cur ^ 1, (st + 1) * BK);
        const u16* Al = &Ab[cur][0];
        const u16* Bl = &Bb[cur][0];
        bf16x8 bf[2];
#pragma unroll
        for (int u = 0; u < 2; ++u)
            bf[u] = *(const bf16x8*)(Bl + (wc * 32 + u * 16 + r) * BK + g * 8);
#pragma unroll
        for (int t = 0; t < MF; ++t) {
            bf16x8 af = *(const bf16x8*)(Al + (wr * 64 + t * 16 + r) * BK + g * 8);
#pragma unroll
            for (int u = 0; u < 2; ++u)
                acc[t][u] = __builtin_amdgcn_mfma_f32_16x16x32_bf16(af, bf[u], acc[t][u], 0, 0, 0);
        }
        __syncthreads();
    }
    constexpr float QS = 0.125f * 1.4426950408889634f;  // 1/sqrt(DH) * log2(e)
    int region = blockIdx.x >> 2;        // 0=q, 1=k, 2=v
    int head = blockIdx.x & 3;
    int r0 = bm + wr * 64 + g * 4;
    if (region == 2) {
#pragma unroll
        for (int t = 0; t < MF; ++t)
#pragma unroll
            for (int u = 0; u < 2; ++u) {
                int d = wc * 32 + u * 16 + r;
                int col = bn + d;
                ushort4 vo;
                vo.x = f2bf(acc[t][u][0] + bias[col]);
                vo.y = f2bf(acc[t][u][1] + bias[col]);
                vo.z = f2bf(acc[t][u][2] + bias[col]);
                vo.w = f2bf(acc[t][u][3] + bias[col]);
                *(ushort4*)(VTb + ((size_t)head * 64 + d) * kN + r0 + t * 16) = vo;
            }
    } else {
        u16* dst = (region == 0) ? Qb : Kb;
        float sc = (region == 0) ? QS : 1.f;
#pragma unroll
        for (int t = 0; t < MF; ++t)
#pragma unroll
            for (int u = 0; u < 2; ++u)
#pragma unroll
                for (int e = 0; e < 4; ++e) {
                    int d = wc * 32 + u * 16 + r;
                    int row = r0 + t * 16 + e;
                    dst[((size_t)head * kN + row) * 64 + d] =
                        f2bf((acc[t][u][e] + bias[bn + d]) * sc);
                }
    }
}

// ---------------- 128x128-tile staged GAT GEMM: xl half -> fp8, xr half -> bf16 ----
template <int K>
__global__ __launch_bounds__(256) void gemm_gat(
    const u16* __restrict__ A, const u16* __restrict__ W,
    u8* __restrict__ Cl, u16* __restrict__ Cr) {
    constexpr int BK = 32;
    constexpr int NK = K / BK;
    int tid = threadIdx.x;
    int w = tid >> 6, lane = tid & 63;
    int wr = w >> 1, wc = w & 1;
    int g = lane >> 4, r = lane & 15;
    int bm = blockIdx.y * 128;
    int bn = blockIdx.x * 128;
    __shared__ __align__(16) u16 Ab[2][128 * BK];
    __shared__ __align__(16) u16 Bb[2][128 * BK];
    int srd = lane >> 2;
    int schunk = ((lane & 3) ^ ((lane >> 3) & 3)) * 8;
    auto stage = [&](int buf, int k0) {
#pragma unroll
        for (int i = 0; i < 2; ++i) {
            int rowA = bm + i * 64 + w * 16 + srd;
            int rowB = bn + i * 64 + w * 16 + srd;
            gload_lds16(A + (size_t)rowA * K + k0 + schunk, &Ab[buf][(i * 64 + w * 16) * BK]);
            gload_lds16(W + (size_t)rowB * K + k0 + schunk, &Bb[buf][(i * 64 + w * 16) * BK]);
        }
    };
    f32x4 acc[4][4] = {};
    stage(0, 0);
    __syncthreads();
    int rs = (r >> 1) & 3;
    for (int st = 0; st < NK; ++st) {
        int cur = st & 1;
        if (st + 1 < NK) stage(cur ^ 1, (st + 1) * BK);
        const u16* Al = &Ab[cur][0];
        const u16* Bl = &Bb[cur][0];
        bf16x8 bf[4];
#pragma unroll
        for (int u = 0; u < 4; ++u)
            bf[u] = *(const bf16x8*)(Bl + (wc * 64 + u * 16 + r) * BK + ((g ^ rs) * 8));
#pragma unroll
        for (int t = 0; t < 4; ++t) {
            bf16x8 af = *(const bf16x8*)(Al + (wr * 64 + t * 16 + r) * BK + ((g ^ rs) * 8));
#pragma unroll
            for (int u = 0; u < 4; ++u)
                acc[t][u] = __builtin_amdgcn_mfma_f32_16x16x32_bf16(af, bf[u], acc[t][u], 0, 0, 0);
        }
        __syncthreads();
    }
    if (bn < 1024) {   // xl half -> fp8 e4m3
#pragma unroll
        for (int t = 0; t < 4; ++t)
#pragma unroll
            for (int u = 0; u < 4; ++u)
#pragma unroll
                for (int e = 0; e < 4; ++e) {
                    int row = bm + wr * 64 + t * 16 + g * 4 + e;
                    int col = bn + wc * 64 + u * 16 + r;
                    int pk = __builtin_amdgcn_cvt_pk_fp8_f32(acc[t][u][e], acc[t][u][e], 0, false);
                    Cl[(size_t)row * 1024 + col] = (u8)(pk & 0xff);
                }
    } else {           // xr half -> bf16
#pragma unroll
        for (int t = 0; t < 4; ++t)
#pragma unroll
            for (int u = 0; u < 4; ++u)
#pragma unroll
                for (int e = 0; e < 4; ++e) {
                    int row = bm + wr * 64 + t * 16 + g * 4 + e;
                    int col = (bn - 1024) + wc * 64 + u * 16 + r;
                    Cr[(size_t)row * 1024 + col] = f2bf(acc[t][u][e]);
                }
    }
}

// ---------------- GEMM (N=256) + fused bias + residual + LayerNorm ----------------
template <int BM, int K>
__global__ __launch_bounds__(256) void gemm_ln(
    const u16* __restrict__ A, const u16* __restrict__ W,
    const float* __restrict__ bias,
    const float* __restrict__ lng, const float* __restrict__ lnb,
    float* __restrict__ h, u16* __restrict__ hbf) {
    constexpr int BK = 32;
    constexpr int NK = K / BK;
    constexpr int MT = BM / 16;
    int tid = threadIdx.x;
    int w = tid >> 6, lane = tid & 63;
    int g = lane >> 4, r = lane & 15;
    int bm = blockIdx.x * BM;
    __shared__ __align__(16) u16 Ab[2][BM * BK];
    __shared__ __align__(16) u16 Bb[2][256 * BK];
    __shared__ float sums[BM][4][2];
    int srd = lane >> 2;
    int schunk = ((lane & 3) ^ ((lane >> 3) & 3)) * 8;
    auto stage = [&](int buf, int k0) {
        if (w < MT)
            gload_lds16(A + (size_t)(bm + w * 16 + srd) * K + k0 + schunk,
                        &Ab[buf][(w * 16) * BK]);
#pragma unroll
        for (int i = 0; i < 4; ++i)
            gload_lds16(W + (size_t)(w * 64 + i * 16 + srd) * K + k0 + schunk,
                        &Bb[buf][(w * 64 + i * 16) * BK]);
    };
    f32x4 acc[MT][4] = {};
    stage(0, 0);
    __syncthreads();
    int rs = (r >> 1) & 3;
    for (int st = 0; st < NK; ++st) {
        int cur = st & 1;
        if (st + 1 < NK) stage(cur ^ 1, (st + 1) * BK);
        const u16* Al = &Ab[cur][0];
        const u16* Bl = &Bb[cur][0];
        bf16x8 bf[4];
#pragma unroll
        for (int u = 0; u < 4; ++u)
            bf[u] = *(const bf16x8*)(Bl + (w * 64 + u * 16 + r) * BK + ((g ^ rs) * 8));
#pragma unroll
        for (int t = 0; t < MT; ++t) {
            bf16x8 af = *(const bf16x8*)(Al + (t * 16 + r) * BK + ((g ^ rs) * 8));
#pragma unroll
            for (int u = 0; u < 4; ++u)
                acc[t][u] = __builtin_amdgcn_mfma_f32_16x16x32_bf16(af, bf[u], acc[t][u], 0, 0, 0);
        }
        __syncthreads();
    }
    float val[MT][4][4];
#pragma unroll
    for (int t = 0; t < MT; ++t)
#pragma unroll
        for (int e = 0; e < 4; ++e) {
            int row = bm + t * 16 + g * 4 + e;
            float s1 = 0.f, s2 = 0.f;
#pragma unroll
            for (int u = 0; u < 4; ++u) {
                int col = w * 64 + u * 16 + r;
                float v = acc[t][u][e] + bias[col] + h[(size_t)row * kC + col];
                val[t][u][e] = v;
                s1 += v;
                s2 += v * v;
            }
            s1 = dpp_ror_add16(s1);
            s2 = dpp_ror_add16(s2);
            if (r == 0) {
                sums[t * 16 + g * 4 + e][w][0] = s1;
                sums[t * 16 + g * 4 + e][w][1] = s2;
            }
        }
    __syncthreads();
#pragma unroll
    for (int t = 0; t < MT; ++t)
#pragma unroll
        for (int e = 0; e < 4; ++e) {
            int lr = t * 16 + g * 4 + e;
            int row = bm + lr;
            float S1 = sums[lr][0][0] + sums[lr][1][0] + sums[lr][2][0] + sums[lr][3][0];
            float S2 = sums[lr][0][1] + sums[lr][1][1] + sums[lr][2][1] + sums[lr][3][1];
            float mu = S1 * (1.f / kC);
            float rstd = rsqrtf(S2 * (1.f / kC) - mu * mu + 1e-5f);
#pragma unroll
            for (int u = 0; u < 4; ++u) {
                int col = w * 64 + u * 16 + r;
                float y = (val[t][u][e] - mu) * rstd * lng[col] + lnb[col];
                h[(size_t)row * kC + col] = y;
                hbf[(size_t)row * kC + col] = f2bf(y);
            }
        }
}

// ---------------- GATv2: per-node online softmax aggregation + fused residual LN ----
__global__ __launch_bounds__(256) void gat_agg(
    const u8* __restrict__ xl8, const u16* __restrict__ xr16,
    const float* __restrict__ att, const float* __restrict__ gb,
    const int* __restrict__ off, const int* __restrict__ srcs,
    const float* __restrict__ lng, const float* __restrict__ lnb,
    float* __restrict__ h, u16* __restrict__ hbf) {
    int n = blockIdx.x;
    int w = threadIdx.x >> 6, lane = threadIdx.x & 63;
    int q = lane >> 4, t = lane & 15;
    int cb = w * 256 + t * 16;   // channel slice [cb, cb+16) of 1024

    uint4 xru0 = *(const uint4*)(xr16 + (size_t)n * 1024 + cb);
    uint4 xru1 = *(const uint4*)(xr16 + (size_t)n * 1024 + cb + 8);
    float xrv[16];
    unpack8(xru0, xrv); unpack8(xru1, xrv + 8);
    float att6[16], att4[16];
#pragma unroll
    for (int j = 0; j < 16; j += 4) {
        float4 a4 = *(const float4*)(att + cb + j);
        att6[j] = 0.6f * a4.x; att6[j + 1] = 0.6f * a4.y;
        att6[j + 2] = 0.6f * a4.z; att6[j + 3] = 0.6f * a4.w;
        att4[j] = (2.f / 3.f) * att6[j]; att4[j + 1] = (2.f / 3.f) * att6[j + 1];
        att4[j + 2] = (2.f / 3.f) * att6[j + 2]; att4[j + 3] = (2.f / 3.f) * att6[j + 3];
    }

    int i0 = off[n], i1 = off[n + 1];
    float m = -1e30f, ls = 0.f;
    float acc[16] = {};
    int i = i0 + q;
    uint4 pa, pb;
    if (i < i1) pa = *(const uint4*)(xl8 + (size_t)srcs[i] * 1024 + cb);
    if (i + 4 < i1) pb = *(const uint4*)(xl8 + (size_t)srcs[i + 4] * 1024 + cb);
    while (i < i1) {
        uint4 c0 = pa;
        pa = pb;
        if (i + 8 < i1) pb = *(const uint4*)(xl8 + (size_t)srcs[i + 8] * 1024 + cb);
        float x[16];
        unpack_fp8x4(c0.x, x);
        unpack_fp8x4(c0.y, x + 4);
        unpack_fp8x4(c0.z, x + 8);
        unpack_fp8x4(c0.w, x + 12);
        float p = 0.f;
#pragma unroll
        for (int j = 0; j < 16; ++j) {
            float e = x[j] + xrv[j];
            p = fmaf(att6[j], e, p);
            p = fmaf(att4[j], __builtin_fabsf(e), p);
        }
        p = dpp_ror_add16(p);   // all 16 lanes of the quarter now hold the score
        if (p > m) {            // quarter-uniform
            float c = __expf(m - p);
            ls = ls * c + 1.f;
#pragma unroll
            for (int j = 0; j < 16; ++j) acc[j] = acc[j] * c + x[j];
            m = p;
        } else {
            float pw = __expf(p - m);
            ls += pw;
#pragma unroll
            for (int j = 0; j < 16; ++j) acc[j] = fmaf(pw, x[j], acc[j]);
        }
        i += 4;
    }
    // exact LSE merge of the 4 quarter states
    float mm = fmaxf(m, __shfl_xor(m, 16));
    mm = fmaxf(mm, __shfl_xor(mm, 32));
    float c = __expf(m - mm);   // 0 for empty quarters (m = -1e30)
    ls *= c;
    ls += __shfl_xor(ls, 16);
    ls += __shfl_xor(ls, 32);
#pragma unroll
    for (int j = 0; j < 16; ++j) {
        float a = acc[j] * c;
        a += __shfl_xor(a, 16);
        a += __shfl_xor(a, 32);
        acc[j] = a;
    }
    float inv = 1.f / ls;
    __shared__ float red[4][256];
    __shared__ float rs[8];
    if (q == 0) {
#pragma unroll
        for (int j = 0; j < 16; ++j) red[w][t * 16 + j] = acc[j] * inv;
    }
    __syncthreads();
    int cc = threadIdx.x;
    float vsum = 0.25f * (red[0][cc] + red[1][cc] + red[2][cc] + red[3][cc]) + gb[cc];
    float v = h[(size_t)n * kC + cc] + vsum;
    float s1 = v, s2 = v * v;
    for (int d = 1; d < 64; d <<= 1) { s1 += __shfl_xor(s1, d); s2 += __shfl_xor(s2, d); }
    if (lane == 0) { rs[w] = s1; rs[4 + w] = s2; }
    __syncthreads();
    s1 = rs[0] + rs[1] + rs[2] + rs[3];
    s2 = rs[4] + rs[5] + rs[6] + rs[7];
    float mu = s1 * (1.f / kC);
    float rstd = rsqrtf(s2 * (1.f / kC) - mu * mu + 1e-5f);
    float y = (v - mu) * rstd * lng[cc] + lnb[cc];
    h[(size_t)n * kC + cc] = y;
    hbf[(size_t)n * kC + cc] = f2bf(y);
}

// ---------------- MFMA flash attention: 128 q-rows/block, time-shared plds --------
// NSPLIT=8 -> grid 1024 blocks = 4 blocks/CU (matches 40KB LDS capacity).
__global__ __launch_bounds__(256, 4) void mha_mfma3(
    const u16* __restrict__ Qb, const u16* __restrict__ Kb,
    const u16* __restrict__ VTb, u16* __restrict__ opart, float* __restrict__ mlpart) {
    int qt = blockIdx.x, head = blockIdx.y, sp = blockIdx.z;
    int tid = threadIdx.x;
    int w = tid >> 6, lane = tid & 63;
    int g = lane >> 4, r = lane & 15;
    int q0 = qt * 128;
    const u16* QhA = Qb + ((size_t)head * kN + q0 + w * 16) * 64;
    const u16* QhB = QhA + (size_t)64 * 64;
    const u16* Kh = Kb + (size_t)head * kN * 64;
    const u16* VTh = VTb + (size_t)head * 64 * kN;
    __shared__ u16 Kt[2][64 * 64];
    __shared__ u16 Vt[2][64 * 64];
    __shared__ u16 plds[4][16 * 64];
    int srow = w * 8 + (lane >> 3);
    int schunk = ((lane & 7) ^ ((lane >> 3) & 7)) * 8;
    int kbase = sp * KSPAN;

    bf16x8 qfA0 = *(const bf16x8*)(QhA + r * 64 + g * 8);
    bf16x8 qfA1 = *(const bf16x8*)(QhA + r * 64 + 32 + g * 8);
    bf16x8 qfB0 = *(const bf16x8*)(QhB + r * 64 + g * 8);
    bf16x8 qfB1 = *(const bf16x8*)(QhB + r * 64 + 32 + g * 8);

    auto stage = [&](int buf, int k0) {
#pragma unroll
        for (int i = 0; i < 2; ++i) {
            int row = i * 32 + srow;
            gload_lds16(Kh + (size_t)(k0 + row) * 64 + schunk, &Kt[buf][(i * 32 + w * 8) * 64]);
            gload_lds16(VTh + (size_t)row * kN + k0 + schunk, &Vt[buf][(i * 32 + w * 8) * 64]);
        }
    };

    f32x4 oA[4] = {}, oB[4] = {};
    float mA = -3.0e38f, lA = 0.f, mB = -3.0e38f, lB = 0.f;

    stage(0, kbase);
    __syncthreads();

    int rx = r & 7;
    for (int st = 0; st < NSTEP; ++st) {
        int cur = st & 1;
        if (st + 1 < NSTEP) stage(cur ^ 1, kbase + (st + 1) * 64);
        const u16* Kl = &Kt[cur][0];
        const u16* Vl = &Vt[cur][0];
        bf16x8 paA0, paA1;
        // ---- set A: QK^T, softmax, P->plds, pull PA frags into regs ----
        {
            f32x4 stt[4] = {};
#pragma unroll
            for (int t = 0; t < 4; ++t) {
                bf16x8 kf0 = *(const bf16x8*)(Kl + (16 * t + r) * 64 + ((0 + g) ^ rx) * 8);
                bf16x8 kf1 = *(const bf16x8*)(Kl + (16 * t + r) * 64 + ((4 + g) ^ rx) * 8);
                stt[t] = __builtin_amdgcn_mfma_f32_16x16x32_bf16(kf0, qfA0, stt[t], 0, 0, 0);
                stt[t] = __builtin_amdgcn_mfma_f32_16x16x32_bf16(kf1, qfA1, stt[t], 0, 0, 0);
            }
            float pm = stt[0][0];
#pragma unroll
            for (int t = 0; t < 4; ++t)
#pragma unroll
                for (int e = 0; e < 4; ++e) pm = fmaxf(pm, stt[t][e]);
            pm = fmaxf(pm, __shfl_xor(pm, 16));
            pm = fmaxf(pm, __shfl_xor(pm, 32));
            if (__any(pm > mA)) {
                float mn = fmaxf(mA, pm);
                float corr = __builtin_amdgcn_exp2f(mA - mn);
                lA *= corr;
                float corrq[4];
#pragma unroll
                for (int e = 0; e < 4; ++e) corrq[e] = __shfl(corr, g * 4 + e);
#pragma unroll
                for (int dt = 0; dt < 4; ++dt)
#pragma unroll
                    for (int e = 0; e < 4; ++e) oA[dt][e] *= corrq[e];
                mA = mn;
            }
            float lsx = 0.f;
#pragma unroll
            for (int t = 0; t < 4; ++t) {
                ushort4 pk;
                float p0 = __builtin_amdgcn_exp2f(stt[t][0] - mA);
                float p1 = __builtin_amdgcn_exp2f(stt[t][1] - mA);
                float p2 = __builtin_amdgcn_exp2f(stt[t][2] - mA);
                float p3 = __builtin_amdgcn_exp2f(stt[t][3] - mA);
                lsx += (p0 + p1) + (p2 + p3);
                pk.x = f2bf(p0); pk.y = f2bf(p1); pk.z = f2bf(p2); pk.w = f2bf(p3);
                int lc = (2 * t + (g >> 1)) ^ rx;
                *(ushort4*)(&plds[w][r * 64 + lc * 8 + (g & 1) * 4]) = pk;
            }
            lsx += __shfl_xor(lsx, 16);
            lsx += __shfl_xor(lsx, 32);
            lA += lsx;
            paA0 = *(const bf16x8*)(&plds[w][r * 64 + (g ^ rx) * 8]);
            paA1 = *(const bf16x8*)(&plds[w][r * 64 + ((4 + g) ^ rx) * 8]);
        }
        // ---- set B: QK^T, softmax, P->plds (reuses buffer after paA reads) ----
        {
            f32x4 stt[4] = {};
#pragma unroll
            for (int t = 0; t < 4; ++t) {
                bf16x8 kf0 = *(const bf16x8*)(Kl + (16 * t + r) * 64 + ((0 + g) ^ rx) * 8);
                bf16x8 kf1 = *(const bf16x8*)(Kl + (16 * t + r) * 64 + ((4 + g) ^ rx) * 8);
                stt[t] = __builtin_amdgcn_mfma_f32_16x16x32_bf16(kf0, qfB0, stt[t], 0, 0, 0);
                stt[t] = __builtin_amdgcn_mfma_f32_16x16x32_bf16(kf1, qfB1, stt[t], 0, 0, 0);
            }
            float pm = stt[0][0];
#pragma unroll
            for (int t = 0; t < 4; ++t)
#pragma unroll
                for (int e = 0; e < 4; ++e) pm = fmaxf(pm, stt[t][e]);
            pm = fmaxf(pm, __shfl_xor(pm, 16));
            pm = fmaxf(pm, __shfl_xor(pm, 32));
            if (__any(pm > mB)) {
                float mn = fmaxf(mB, pm);
                float corr = __builtin_amdgcn_exp2f(mB - mn);
                lB *= corr;
                float corrq[4];
#pragma unroll
                for (int e = 0; e < 4; ++e) corrq[e] = __shfl(corr, g * 4 + e);
#pragma unroll
                for (int dt = 0; dt < 4; ++dt)
#pragma unroll
                    for (int e = 0; e < 4; ++e) oB[dt][e] *= corrq[e];
                mB = mn;
            }
            float lsx = 0.f;
#pragma unroll
            for (int t = 0; t < 4; ++t) {
                ushort4 pk;
                float p0 = __builtin_amdgcn_exp2f(stt[t][0] - mB);
                float p1 = __builtin_amdgcn_exp2f(stt[t][1] - mB);
                float p2 = __builtin_amdgcn_exp2f(stt[t][2] - mB);
                float p3 = __builtin_amdgcn_exp2f(stt[t][3] - mB);
                lsx += (p0 + p1) + (p2 + p3);
                pk.x = f2bf(p0); pk.y = f2bf(p1); pk.z = f2bf(p2); pk.w = f2bf(p3);
                int lc = (2 * t + (g >> 1)) ^ rx;
                *(ushort4*)(&plds[w][r * 64 + lc * 8 + (g & 1) * 4]) = pk;
            }
            lsx += __shfl_xor(lsx, 16);
            lsx += __shfl_xor(lsx, 32);
            lB += lsx;
        }
        bf16x8 paB0 = *(const bf16x8*)(&plds[w][r * 64 + (g ^ rx) * 8]);
        bf16x8 paB1 = *(const bf16x8*)(&plds[w][r * 64 + ((4 + g) ^ rx) * 8]);
        // ---- PV: vf reads shared across both sets ----
#pragma unroll
        for (int dt = 0; dt < 4; ++dt) {
            bf16x8 vf0 = *(const bf16x8*)(Vl + (dt * 16 + r) * 64 + ((0 + g) ^ rx) * 8);
            bf16x8 vf1 = *(const bf16x8*)(Vl + (dt * 16 + r) * 64 + ((4 + g) ^ rx) * 8);
            oA[dt] = __builtin_amdgcn_mfma_f32_16x16x32_bf16(paA0, vf0, oA[dt], 0, 0, 0);
            oA[dt] = __builtin_amdgcn_mfma_f32_16x16x32_bf16(paA1, vf1, oA[dt], 0, 0, 0);
            oB[dt] = __builtin_amdgcn_mfma_f32_16x16x32_bf16(paB0, vf0, oB[dt], 0, 0, 0);
            oB[dt] = __builtin_amdgcn_mfma_f32_16x16x32_bf16(paB1, vf1, oB[dt], 0, 0, 0);
        }
        __syncthreads();
    }

    size_t slot = (size_t)(head * 32 + qt) * NSPLIT + sp;
    u16* ob = opart + slot * 8192;
#pragma unroll
    for (int dt = 0; dt < 4; ++dt)
#pragma unroll
        for (int e = 0; e < 4; ++e) {
            ob[(w * 16 + g * 4 + e) * 64 + dt * 16 + r] = f2bf(oA[dt][e]);
            ob[(64 + w * 16 + g * 4 + e) * 64 + dt * 16 + r] = f2bf(oB[dt][e]);
        }
    float* mlb = mlpart + slot * 256;
    if (g == 0) {
        mlb[w * 16 + r] = mA;
        mlb[64 + w * 16 + r] = mB;
        mlb[128 + w * 16 + r] = lA;
        mlb[192 + w * 16 + r] = lB;
    }
}

// ---------------- merge split-K attention partials -> attnb (bf16) ----------------
__global__ __launch_bounds__(256) void mha_merge(
    const u16* __restrict__ opart, const float* __restrict__ mlpart,
    u16* __restrict__ attnb) {
    int head = blockIdx.y;
    int q = blockIdx.x * 4 + (threadIdx.x >> 6);
    int d = threadIdx.x & 63;
    int qt = q >> 7, ql = q & 127;
    size_t sb = (size_t)(head * 32 + qt) * NSPLIT;
    float ms[NSPLIT], lsv[NSPLIT];
    float mstar = -3.0e38f;
#pragma unroll
    for (int s = 0; s < NSPLIT; ++s) {
        ms[s] = mlpart[(sb + s) * 256 + ql];
        lsv[s] = mlpart[(sb + s) * 256 + 128 + ql];
        mstar = fmaxf(mstar, ms[s]);
    }
    float acc = 0.f, lsum = 0.f;
#pragma unroll
    for (int s = 0; s < NSPLIT; ++s) {
        float wgt = __builtin_amdgcn_exp2f(ms[s] - mstar);
        lsum += lsv[s] * wgt;
        acc += bf2f(opart[(sb + s) * 8192 + ql * 64 + d]) * wgt;
    }
    attnb[(size_t)q * kC + head * 64 + d] = f2bf(acc / lsum);
}

// ---------------- final: out[4096,2] = t_bf @ out_w2^T + b2; wave per row ----------------
__global__ __launch_bounds__(256) void final_out(
    const u16* __restrict__ tbf, const float* __restrict__ w2,
    const float* __restrict__ b2, float* __restrict__ out) {
    int row = blockIdx.x * 4 + (threadIdx.x >> 6);
    int lane = threadIdx.x & 63;
    const ushort4 tv = *(const ushort4*)(tbf + (size_t)row * 256 + lane * 4);
    float t0 = bf2f(tv.x), t1 = bf2f(tv.y), t2 = bf2f(tv.z), t3 = bf2f(tv.w);
    const float4 w0 = *(const float4*)(w2 + lane * 4);
    const float4 w1 = *(const float4*)(w2 + 256 + lane * 4);
    float d0 = t0 * w0.x + t1 * w0.y + t2 * w0.z + t3 * w0.w;
    float d1 = t0 * w1.x + t1 * w1.y + t2 * w1.z + t3 * w1.w;
    for (int d = 1; d < 64; d <<= 1) { d0 += __shfl_xor(d0, d); d1 += __shfl_xor(d1, d); }
    if (lane == 0) {
        out[(size_t)row * 2 + 0] = d0 + b2[0];
        out[(size_t)row * 2 + 1] = d1 + b2[1];
    }
}

extern "C" void kernel_launch(void* const* d_in, const int* in_sizes, int n_in,
                              void* d_out, int out_size, void* d_ws, size_t ws_size,
                              hipStream_t stream) {
    (void)in_sizes; (void)n_in; (void)out_size;
    const float* x        = (const float*)d_in[0];
    const int*   ei       = (const int*)d_in[1];
    const float* in_w     = (const float*)d_in[2];
    const float* in_b     = (const float*)d_in[3];
    const float* gat_wl   = (const float*)d_in[4];
    const float* gat_wr   = (const float*)d_in[5];
    const float* gat_att  = (const float*)d_in[6];
    const float* gat_b    = (const float*)d_in[7];
    const float* mha_in_w = (const float*)d_in[8];
    const float* mha_in_b = (const float*)d_in[9];
    const float* mha_out_w= (const float*)d_in[10];
    const float* mha_out_b= (const float*)d_in[11];
    const float* ln1_g = (const float*)d_in[12];
    const float* ln1_b = (const float*)d_in[13];
    const float* ln2_g = (const float*)d_in[14];
    const float* ln2_b = (const float*)d_in[15];
    const float* ln3_g = (const float*)d_in[16];
    const float* ln3_b = (const float*)d_in[17];
    const float* ffn_w1 = (const float*)d_in[18];
    const float* ffn_b1 = (const float*)d_in[19];
    const float* ffn_w2 = (const float*)d_in[20];
    const float* ffn_b2 = (const float*)d_in[21];
    const float* out_w1 = (const float*)d_in[22];
    const float* out_b1 = (const float*)d_in[23];
    const float* out_w2 = (const float*)d_in[24];
    const float* out_b2 = (const float*)d_in[25];
    float* out = (float*)d_out;

    char* ws = (char*)d_ws;
    size_t off = 0;
    auto alloc = [&](size_t bytes) -> void* {
        void* p = (void*)(ws + off);
        off += (bytes + 255) & ~(size_t)255;
        return p;
    };
    float* h     = (float*)alloc((size_t)kN * kC * 4);
    u16*   hbf   = (u16*)  alloc((size_t)kN * kC * 2);
    float* xlb   = (float*)alloc((size_t)kN * 1024 * 4);   // slot reused: xl8+xr16 / Qb+Kb+VTb
    float* xrb   = (float*)alloc((size_t)kN * 1024 * 4);   // slot reused: opart (bf16, 16 MB)
    float* locb  = (float*)alloc((size_t)kN * kC * 4);     // slot reused: mlpart (1 MB)
    u16*   attnb = (u16*)  alloc((size_t)kN * kC * 2);
    u16*   midb  = (u16*)  alloc((size_t)kN * 512 * 2);
    u16*   tbf   = (u16*)  alloc((size_t)kN * kC * 2);
    u16*   xbf   = (u16*)  alloc((size_t)kN * kIn * 2);
    u16*   wbf   = (u16*)  alloc((size_t)3342336 * 2);
    int*   coff  = (int*)  alloc((size_t)4097 * 4);
    int*   ccur  = (int*)  alloc((size_t)4096 * 4);
    int*   csrc  = (int*)  alloc((size_t)kET * 4);
    if (ws_size < off) return;  // not enough scratch: bail loudly (output stays poisoned)

    // GAT transform outputs: xl in fp8 (4 MB, gathered, ~L2-resident), xr in bf16 (8 MB).
    u8*  xl8  = (u8*)xlb;                        // [4096][1024] fp8
    u16* xr16 = (u16*)((char*)xlb + (size_t)kN * 1024);  // [4096][1024] bf16
    // MHA operands alias the same 16 MB slot (xl8/xr16 dead after gat_agg).
    u16* Qb  = (u16*)xlb;                        // [4][4096][64]
    u16* Kb  = Qb + (size_t)4 * kN * 64;         // [4][4096][64]
    u16* VTb = Kb + (size_t)4 * kN * 64;         // [4][64][4096]
    u16*   opart  = (u16*)xrb;                   // 1024 slots x 8192 bf16 = 16 MB exact
    float* mlpart = locb;                        // 1024 x 256 f32 = 1 MB

    // bf16 weight buffer offsets (elements); gat wl/wr interleaved per layer [2048][256]
    const size_t OFF_INW  = 0;
    const size_t OFF_GAT  = 131072;
    const size_t OFF_MIN  = 1703936;
    const size_t OFF_MOUT = 2293760;
    const size_t OFF_F1   = 2490368;
    const size_t OFF_F2   = 2883584;
    const size_t OFF_O1   = 3276800;

    // CSR count is fused into cast_all -> zero the counters first
    hipMemsetAsync(ccur, 0, 4096 * 4, stream);
    cast_all<<<dim3(1495040 / 256), dim3(256), 0, stream>>>(
        x, in_w, gat_wl, gat_wr, mha_in_w, mha_out_w, ffn_w1, ffn_w2, out_w1,
        xbf, wbf, ei, ccur);
    csr_scan<<<dim3(1), dim3(1024), 0, stream>>>(ccur, coff);
    csr_scatter<<<dim3((kET + 255) / 256), dim3(256), 0, stream>>>(ei, ccur, csrc);

    // input projection: h = x @ in_w^T + in_b  (fp32 + bf16 outputs)
    gemm_st<64, 512, 0, 1, 1><<<dim3(kC / 64, kN / 64), dim3(256), 0, stream>>>(
        xbf, wbf + OFF_INW, in_b, h, hbf, kC);

    for (int l = 0; l < kL; ++l) {
        // GATv2 transforms: fused wl|wr 128x128-tile GEMM -> xl8 (fp8) + xr16 (bf16)
        gemm_gat<256><<<dim3(2048 / 128, kN / 128), dim3(256), 0, stream>>>(
            hbf, wbf + OFF_GAT + (size_t)l * 524288, xl8, xr16);
        // gat_agg with fused residual + ln1 (writes h, hbf directly)
        gat_agg<<<dim3(kN), dim3(256), 0, stream>>>(
            xl8, xr16, gat_att + (size_t)l * 1024, gat_b + (size_t)l * kC, coff, csrc,
            ln1_g + (size_t)l * kC, ln1_b + (size_t)l * kC, h, hbf);

        // MHA: fused qkv GEMM writes Qb/Kb/VTb directly
        gemm_qkv<<<dim3(768 / 64, kN / 128), dim3(256), 0, stream>>>(
            hbf, wbf + OFF_MIN + (size_t)l * 768 * kC, mha_in_b + (size_t)l * 768,
            Qb, Kb, VTb);
        mha_mfma3<<<dim3(kN / 128, 4, NSPLIT), dim3(256), 0, stream>>>(Qb, Kb, VTb, opart, mlpart);
        mha_merge<<<dim3(kN / 4, 4), dim3(256), 0, stream>>>(opart, mlpart, attnb);
        // mout GEMM + fused residual + ln2
        gemm_ln<16, 256><<<dim3(kN / 16), dim3(256), 0, stream>>>(
            attnb, wbf + OFF_MOUT + (size_t)l * kC * kC, mha_out_b + (size_t)l * kC,
            ln2_g + (size_t)l * kC, ln2_b + (size_t)l * kC, h, hbf);

        // FFN: ffn1 GEMM (+gelu) then ffn2 GEMM + fused residual + ln3
        gemm_st<64, 256, 1, 0, 1><<<dim3(512 / 64, kN / 64), dim3(256), 0, stream>>>(
            hbf, wbf + OFF_F1 + (size_t)l * 512 * kC, ffn_b1 + (size_t)l * 512, nullptr, midb, 512);
        gemm_ln<16, 512><<<dim3(kN / 16), dim3(256), 0, stream>>>(
            midb, wbf + OFF_F2 + (size_t)l * kC * 512, ffn_b2 + (size_t)l * kC,
            ln3_g + (size_t)l * kC, ln3_b + (size_t)l * kC, h, hbf);
    }

    // output head
    gemm_st<64, 256, 1, 0, 1><<<dim3(kC / 64, kN / 64), dim3(256), 0, stream>>>(
        hbf, wbf + OFF_O1, out_b1, nullptr, tbf, kC);
    final_out<<<dim3(kN / 4), dim3(256), 0, stream>>>(tbf, out_w2, out_b2, out);
}